// Round 4
// baseline (960.931 us; speedup 1.0000x reference)
//
#include <hip/hip_runtime.h>
#include <stdint.h>

#define LOG_N     18
#define N_PER     262144            // 2^18 elements per array (H*W)
#define BATCHES   64
#define TPB       256
#define IPT       16
#define TILE      4096              // TPB * IPT
#define TILES_PER_SEG 64            // N_PER / TILE
#define BINS      256

#define ITPB      256               // integ threads per block
#define TPM       32                // merged elements per thread
#define IBLK      (ITPB * TPM)      // 8192 merged elements per block
#define IBPB      ((2 * N_PER) / IBLK) // 64 blocks per batch

__device__ __forceinline__ uint32_t f2u(float f) {
    uint32_t u = __float_as_uint(f);
    return (u & 0x80000000u) ? ~u : (u | 0x80000000u);
}
__device__ __forceinline__ float u2f(uint32_t x) {
    uint32_t u = (x & 0x80000000u) ? (x ^ 0x80000000u) : ~x;
    return __uint_as_float(u);
}

__global__ void init_losses(double* losses) {
    losses[threadIdx.x] = 0.0;
}

// ONE read of the input produces all 4 passes' per-segment histograms.
// LDS layout [pass][bin][sub] with sub = tid&3: hot bins (exponent byte of
// normal data) spread over 4 sub-counters/banks to cut atomic serialization.
__global__ __launch_bounds__(TPB) void hist4_kernel(
        const float* t1, const float* t2, int base_seg, uint32_t* seg_hist) {
    __shared__ uint32_t h[4 * BINS * 4];
    int tile = blockIdx.x;
    int segL = tile >> 6;
    int t    = tile & (TILES_PER_SEG - 1);
    for (int i = threadIdx.x; i < 4 * BINS * 4; i += TPB) h[i] = 0;
    __syncthreads();
    int seg = base_seg + segL;
    const float* p = ((seg & 1) ? t2 : t1) + ((size_t)(seg >> 1) << LOG_N) + (size_t)t * TILE;
    int sub = threadIdx.x & 3;
    for (int k = threadIdx.x; k < TILE; k += TPB) {
        uint32_t u = f2u(p[k]);
        atomicAdd(&h[((u & 255u) << 2) + sub], 1u);
        atomicAdd(&h[(BINS * 4) + (((u >> 8) & 255u) << 2) + sub], 1u);
        atomicAdd(&h[(2 * BINS * 4) + (((u >> 16) & 255u) << 2) + sub], 1u);
        atomicAdd(&h[(3 * BINS * 4) + ((u >> 24) << 2) + sub], 1u);
    }
    __syncthreads();
    for (int i = threadIdx.x; i < 4 * BINS; i += TPB) {
        uint32_t s = h[i * 4] + h[i * 4 + 1] + h[i * 4 + 2] + h[i * 4 + 3];
        if (s) atomicAdd(&seg_hist[(size_t)segL * (4 * BINS) + i], s);
    }
}

// Onesweep scatter: ballot-match stable rank (unchanged), tile offsets via
// decoupled lookback (status = flag<<24 | count), segment digit base via
// in-block scan of seg_hist. Replaces the old hist+scan+scatter triple.
__global__ __launch_bounds__(TPB) void scatter_os_kernel(
        const float* t1, const float* t2, const uint32_t* src, uint32_t* dst,
        const uint32_t* seg_hist, uint32_t* statusP, int pass, int base_seg) {
    __shared__ uint32_t whist[4 * BINS];
    __shared__ uint32_t lkeys[TILE];
    __shared__ uint32_t tstart[BINS];
    __shared__ uint32_t gb[BINS];
    __shared__ uint32_t saA[BINS], sbA[BINS], saB[BINS], sbB[BINS];

    int tile = blockIdx.x;
    int segL = tile >> 6;
    int t    = tile & (TILES_PER_SEG - 1);
    int shift = pass * 8;
    int tid = threadIdx.x;
    int w = tid >> 6, l = tid & 63;
    uint64_t below = (1ull << l) - 1ull;

    whist[tid] = 0; whist[tid + 256] = 0; whist[tid + 512] = 0; whist[tid + 768] = 0;
    __syncthreads();

    uint32_t keys[IPT];
    uint32_t rnk[IPT];
    const float* p0 = nullptr;
    if (pass == 0) {
        int seg = base_seg + segL;
        p0 = ((seg & 1) ? t2 : t1) + ((size_t)(seg >> 1) << LOG_N) + (size_t)t * TILE;
    }
#pragma unroll
    for (int j = 0; j < IPT; ++j) {
        int posL = w * (64 * IPT) + j * 64 + l;   // tile order: wave-block, iter, lane
        uint32_t key;
        if (pass == 0) key = f2u(p0[posL]);
        else           key = src[(size_t)tile * TILE + posL];
        uint32_t d = (key >> shift) & 255u;
        uint64_t peers = ~0ull;
#pragma unroll
        for (int bb = 0; bb < 8; ++bb) {
            uint64_t m = __ballot((d >> bb) & 1u);
            peers &= ((d >> bb) & 1u) ? m : ~m;
        }
        uint32_t rig = (uint32_t)__popcll(peers & below);
        uint32_t cnt = (uint32_t)__popcll(peers);
        if (rig == 0) whist[w * BINS + d] += cnt;   // one leader per digit-group
        __builtin_amdgcn_wave_barrier();
        uint32_t h = whist[w * BINS + d];           // same-wave DS ops are ordered
        keys[j] = key;
        rnk[j] = h - cnt + rig;                     // stable rank within wave
    }
    __syncthreads();

    int d = tid;
    uint32_t c0 = whist[d], c1 = whist[BINS + d], c2 = whist[2 * BINS + d], c3 = whist[3 * BINS + d];
    uint32_t cnt = c0 + c1 + c2 + c3;

    // publish aggregate (or inclusive for tile 0) EARLY so successors progress
    {
        uint32_t flag = (t == 0) ? 2u : 1u;
        __hip_atomic_store(&statusP[(size_t)tile * BINS + d], (flag << 24) | cnt,
                           __ATOMIC_RELAXED, __HIP_MEMORY_SCOPE_AGENT);
    }
    whist[d] = 0;
    whist[BINS + d] = c0;
    whist[2 * BINS + d] = c0 + c1;
    whist[3 * BINS + d] = c0 + c1 + c2;
    saA[d] = cnt;
    saB[d] = seg_hist[(size_t)segL * (4 * BINS) + pass * BINS + d];
    __syncthreads();

    // combined inclusive scans over digits: tile totals + segment totals
    {
        uint32_t* curA = saA; uint32_t* nxtA = sbA;
        uint32_t* curB = saB; uint32_t* nxtB = sbB;
        for (int off = 1; off < BINS; off <<= 1) {
            uint32_t vA = curA[d] + ((d >= off) ? curA[d - off] : 0u);
            uint32_t vB = curB[d] + ((d >= off) ? curB[d - off] : 0u);
            nxtA[d] = vA; nxtB[d] = vB;
            __syncthreads();
            uint32_t* tmp;
            tmp = curA; curA = nxtA; nxtA = tmp;
            tmp = curB; curB = nxtB; nxtB = tmp;
        }
        tstart[d] = (d == 0) ? 0u : curA[d - 1];
        uint32_t segb = (d == 0) ? 0u : curB[d - 1];

        // decoupled lookback for tile-exclusive per-digit offset
        uint32_t excl = 0;
        if (t > 0) {
            int tp = tile - 1;
            int tstop = tile - t;        // first tile of this segment
            while (tp >= tstop) {
                uint32_t v;
                do {
                    v = __hip_atomic_load(&statusP[(size_t)tp * BINS + d],
                                          __ATOMIC_RELAXED, __HIP_MEMORY_SCOPE_AGENT);
                    if (!(v >> 24)) __builtin_amdgcn_s_sleep(1);
                } while (!(v >> 24));
                excl += v & 0xFFFFFFu;
                if ((v >> 24) == 2u) break;
                --tp;
            }
            __hip_atomic_store(&statusP[(size_t)tile * BINS + d], (2u << 24) | (excl + cnt),
                               __ATOMIC_RELAXED, __HIP_MEMORY_SCOPE_AGENT);
        }
        gb[d] = segb + excl;
    }
    __syncthreads();

#pragma unroll
    for (int j = 0; j < IPT; ++j) {
        uint32_t dd = (keys[j] >> shift) & 255u;
        uint32_t lp = tstart[dd] + whist[w * BINS + dd] + rnk[j];
        lkeys[lp] = keys[j];
    }
    __syncthreads();
#pragma unroll
    for (int j = 0; j < IPT; ++j) {
        int i = w * (64 * IPT) + j * 64 + l;
        uint32_t key = lkeys[i];
        uint32_t dd = (key >> shift) & 255u;
        uint32_t pos = gb[dd] + (uint32_t)i - tstart[dd];
        dst[((size_t)segL << LOG_N) + pos] = key;
    }
}

// LDS merge-path integration (unchanged from R3).
__global__ __launch_bounds__(ITPB) void integ_kernel(
        const uint32_t* sorted, double* losses, int base_batch) {
    __shared__ uint32_t lbuf[IBLK + 4];
    __shared__ double red[ITPB];

    int blk = blockIdx.x;
    int bl  = blk / IBPB;
    int pb  = blk % IBPB;
    const uint32_t* A = sorted + ((size_t)(2 * bl) << LOG_N);
    const uint32_t* B = A + N_PER;
    const int n = N_PER;
    int g0 = pb * IBLK;
    int g1 = g0 + IBLK;

    int ia0, ia1;
    {
        int lo = g0 - n; if (lo < 0) lo = 0;
        int hi = g0 < n ? g0 : n;
        while (lo < hi) { int mid = (lo + hi + 1) >> 1; if (A[mid - 1] <= B[g0 - mid]) lo = mid; else hi = mid - 1; }
        ia0 = lo;
    }
    {
        int lo = g1 - n; if (lo < 0) lo = 0;
        int hi = g1 < n ? g1 : n;
        while (lo < hi) { int mid = (lo + hi + 1) >> 1; if (A[mid - 1] <= B[g1 - mid]) lo = mid; else hi = mid - 1; }
        ia1 = lo;
    }
    int jb0 = g0 - ia0, jb1 = g1 - ia1;
    int nA = ia1 - ia0, nB = jb1 - jb0;

    uint32_t* lA = lbuf;
    uint32_t* lB = lbuf + nA + 1;
    for (int k = threadIdx.x; k <= nA; k += ITPB) {
        int gi = ia0 + k;
        lA[k] = (gi < n) ? A[gi] : 0xFFFFFFFFu;
    }
    for (int k = threadIdx.x; k <= nB; k += ITPB) {
        int gj = jb0 + k;
        lB[k] = (gj < n) ? B[gj] : 0xFFFFFFFFu;
    }
    __syncthreads();

    int t0 = (int)threadIdx.x * TPM;
    int lo = t0 - nB; if (lo < 0) lo = 0;
    int hi = t0 < nA ? t0 : nA;
    while (lo < hi) { int mid = (lo + hi + 1) >> 1; if (lA[mid - 1] <= lB[t0 - mid]) lo = mid; else hi = mid - 1; }
    int li = lo, lj = t0 - lo;

    int p0 = g0 + t0;
    int steps = 2 * n - 1 - p0; if (steps > TPM) steps = TPM;

    uint32_t ca = lA[li], cb = lB[lj];
    uint32_t prev;
    if (ca <= cb) { prev = ca; ++li; ca = lA[li]; }
    else          { prev = cb; ++lj; cb = lB[lj]; }
    int d = (ia0 + li) - (jb0 + lj);
    double acc = 0.0;
    for (int s = 0; s < steps; ++s) {
        bool ta = (ca <= cb);
        uint32_t nxt = ta ? ca : cb;
        float delta = u2f(nxt) - u2f(prev);
        double dd = (double)d;
        acc += dd * dd * (double)delta;
        if (ta) { ++li; ca = lA[li]; ++d; }
        else    { ++lj; cb = lB[lj]; --d; }
        prev = nxt;
    }

    red[threadIdx.x] = acc;
    __syncthreads();
    for (int off = ITPB / 2; off > 0; off >>= 1) {
        if ((int)threadIdx.x < off) red[threadIdx.x] += red[threadIdx.x + off];
        __syncthreads();
    }
    if (threadIdx.x == 0) atomicAdd(&losses[base_batch + bl], red[0]);
}

__global__ void final_kernel(const double* losses, float* out) {
    int tid = threadIdx.x;   // 64 threads
    const double inv = 1.0 / ((double)N_PER * (double)N_PER);
    double loss = sqrt(losses[tid] * inv);
    for (int off = 32; off > 0; off >>= 1)
        loss += __shfl_down(loss, off);
    if (tid == 0) out[0] = (float)(loss / (double)BATCHES);
}

extern "C" void kernel_launch(void* const* d_in, const int* in_sizes, int n_in,
                              void* d_out, int out_size, void* d_ws, size_t ws_size,
                              hipStream_t stream) {
    const float* t1 = (const float*)d_in[0];
    const float* t2 = (const float*)d_in[1];
    float* out = (float*)d_out;

    char* ws = (char*)d_ws;
    double* losses = (double*)ws;
    size_t off = 1024;
    size_t perBatchKeys = (size_t)2 << LOG_N;                      // 2^19 keys
    size_t perBatchBuf  = perBatchKeys * 4;                        // 2 MB
    size_t perBatchHist = (size_t)2 * 4 * BINS * 4;                // 2 segs * 4KB
    size_t perBatchStat = (size_t)4 * 2 * TILES_PER_SEG * BINS * 4; // 4 passes * 2 segs * 64KB
    size_t perBatch = 2 * perBatchBuf + perBatchHist + perBatchStat;

    if (ws_size < off + perBatch) return;   // clean failure > GPU fault

    int CB = (int)((ws_size - off) / perBatch);
    if (CB > BATCHES) CB = BATCHES;
    uint32_t* bufA = (uint32_t*)(ws + off);
    uint32_t* bufB = bufA + (size_t)CB * perBatchKeys;
    uint32_t* seg_hist = (uint32_t*)(bufB + (size_t)CB * perBatchKeys);
    uint32_t* status   = seg_hist + (size_t)CB * 2 * 4 * BINS;
    size_t zero_bytes  = (size_t)CB * (perBatchHist + perBatchStat);

    hipLaunchKernelGGL(init_losses, dim3(1), dim3(BATCHES), 0, stream, losses);

    for (int base = 0; base < BATCHES; base += CB) {
        int nb = BATCHES - base < CB ? BATCHES - base : CB;
        int nseg = 2 * nb;
        int ntile = nseg * TILES_PER_SEG;
        size_t statPassStride = (size_t)ntile * BINS;

        hipMemsetAsync(seg_hist, 0, zero_bytes, stream);
        hipLaunchKernelGGL(hist4_kernel, dim3(ntile), dim3(TPB), 0, stream,
                           t1, t2, 2 * base, seg_hist);

        const uint32_t* src = nullptr;
        uint32_t* dst = bufA;
        for (int pass = 0; pass < 4; ++pass) {
            hipLaunchKernelGGL(scatter_os_kernel, dim3(ntile), dim3(TPB), 0, stream,
                               t1, t2, src, dst, seg_hist,
                               status + (size_t)pass * statPassStride, pass, 2 * base);
            src = dst;
            dst = (dst == bufA) ? bufB : bufA;
        }
        hipLaunchKernelGGL(integ_kernel, dim3(nb * IBPB), dim3(ITPB), 0, stream,
                           src, losses, base);
    }
    hipLaunchKernelGGL(final_kernel, dim3(1), dim3(BATCHES), 0, stream, losses, out);
}

// Round 5
// 341.547 us; speedup vs baseline: 2.8135x; 2.8135x over previous
//
#include <hip/hip_runtime.h>
#include <stdint.h>

#define LOG_N     18
#define N_PER     262144            // 2^18 elements per array (H*W)
#define BATCHES   64
#define TPB       256
#define IPT       16
#define TILE      4096              // keys per tile = TPB * IPT
#define TILES_PER_SEG 64            // N_PER / TILE
#define BINS      256

#define ITPB      256               // integ threads per block
#define TPM       32                // merged elements per thread
#define IBLK      (ITPB * TPM)      // 8192 merged elements per block
#define IBPB      ((2 * N_PER) / IBLK) // 64 blocks per batch

__device__ __forceinline__ uint32_t f2u(float f) {
    uint32_t u = __float_as_uint(f);
    return (u & 0x80000000u) ? ~u : (u | 0x80000000u);
}
// value of a truncated 16-bit key (low mantissa bits zero)
__device__ __forceinline__ float u16f(uint32_t k16) {
    uint32_t x = k16 << 16;
    uint32_t u = (x & 0x80000000u) ? (x ^ 0x80000000u) : ~x;
    return __uint_as_float(u);
}

__global__ void init_losses(double* losses) {
    losses[threadIdx.x] = 0.0;
}

// Fused convert + pass-0 histogram: ONE fp32 read produces u16 keys and
// per-tile low-byte histograms. 4-way sub-banked counters.
__global__ __launch_bounds__(TPB) void conv_hist_kernel(
        const float* t1, const float* t2, int base_seg,
        ushort* keys, uint32_t* hist) {
    __shared__ uint32_t h[BINS * 4];
    int tile = blockIdx.x;
    int segL = tile >> 6;
    int t    = tile & (TILES_PER_SEG - 1);
    int tid  = threadIdx.x;
    for (int i = tid; i < BINS * 4; i += TPB) h[i] = 0;
    __syncthreads();
    int seg = base_seg + segL;
    const float4* p = (const float4*)(((seg & 1) ? t2 : t1)
                      + ((size_t)(seg >> 1) << LOG_N) + (size_t)t * TILE);
    uint2* kp = (uint2*)(keys + (size_t)tile * TILE);
    int sub = tid & 3;
    for (int k = 0; k < IPT / 4; ++k) {
        float4 v = p[tid + k * TPB];
        uint32_t k0 = f2u(v.x) >> 16, k1 = f2u(v.y) >> 16;
        uint32_t k2 = f2u(v.z) >> 16, k3 = f2u(v.w) >> 16;
        uint2 pk; pk.x = k0 | (k1 << 16); pk.y = k2 | (k3 << 16);
        kp[tid + k * TPB] = pk;
        atomicAdd(&h[((k0 & 255u) << 2) + sub], 1u);
        atomicAdd(&h[((k1 & 255u) << 2) + sub], 1u);
        atomicAdd(&h[((k2 & 255u) << 2) + sub], 1u);
        atomicAdd(&h[((k3 & 255u) << 2) + sub], 1u);
    }
    __syncthreads();
    for (int i = tid; i < BINS; i += TPB)
        hist[(size_t)tile * BINS + i] =
            h[i * 4] + h[i * 4 + 1] + h[i * 4 + 2] + h[i * 4 + 3];
}

// Pass-1 histogram over u16 keys (high byte, heavily skewed -> 8-way sub-bank).
__global__ __launch_bounds__(TPB) void hist_hi_kernel(
        const ushort* src, uint32_t* hist) {
    __shared__ uint32_t h[BINS * 8];
    int tile = blockIdx.x;
    int tid  = threadIdx.x;
    for (int i = tid; i < BINS * 8; i += TPB) h[i] = 0;
    __syncthreads();
    const uint4* p = (const uint4*)(src + (size_t)tile * TILE);
    int sub = tid & 7;
    for (int k = 0; k < TILE / 8 / TPB; ++k) {   // 2 iterations
        uint4 v = p[tid + k * TPB];
        uint32_t w;
        w = v.x; atomicAdd(&h[(((w & 0xFFFFu) >> 8) << 3) + sub], 1u);
                 atomicAdd(&h[((w >> 24) << 3) + sub], 1u);
        w = v.y; atomicAdd(&h[(((w & 0xFFFFu) >> 8) << 3) + sub], 1u);
                 atomicAdd(&h[((w >> 24) << 3) + sub], 1u);
        w = v.z; atomicAdd(&h[(((w & 0xFFFFu) >> 8) << 3) + sub], 1u);
                 atomicAdd(&h[((w >> 24) << 3) + sub], 1u);
        w = v.w; atomicAdd(&h[(((w & 0xFFFFu) >> 8) << 3) + sub], 1u);
                 atomicAdd(&h[((w >> 24) << 3) + sub], 1u);
    }
    __syncthreads();
    for (int i = tid; i < BINS; i += TPB) {
        uint32_t s = 0;
        for (int q = 0; q < 8; ++q) s += h[i * 8 + q];
        hist[(size_t)tile * BINS + i] = s;
    }
}

// Per-segment scan: hist[tile][bin] -> within-segment exclusive offsets
// (bin-major over segment, tile-minor within bin). One block per segment.
__global__ __launch_bounds__(BINS) void scan_kernel(uint32_t* hist) {
    __shared__ uint32_t sa[BINS], sb[BINS];
    int segL = blockIdx.x;
    int b = threadIdx.x;
    size_t base = (size_t)segL * TILES_PER_SEG * BINS;
    uint32_t s = 0;
#pragma unroll 8
    for (int t = 0; t < TILES_PER_SEG; ++t)
        s += hist[base + (size_t)t * BINS + b];
    sa[b] = s;
    __syncthreads();
    uint32_t* cur = sa; uint32_t* nxt = sb;
    for (int off = 1; off < BINS; off <<= 1) {
        uint32_t v = cur[b] + ((b >= off) ? cur[b - off] : 0u);
        nxt[b] = v;
        __syncthreads();
        uint32_t* tmp = cur; cur = nxt; nxt = tmp;
    }
    uint32_t run = (b == 0) ? 0u : cur[b - 1];
#pragma unroll 8
    for (int t = 0; t < TILES_PER_SEG; ++t) {
        size_t idx = base + (size_t)t * BINS + b;
        uint32_t c = hist[idx];
        hist[idx] = run;
        run += c;
    }
}

// Stable u16 scatter: wave ballot-match ranking, LDS reorder, coalesced write.
__global__ __launch_bounds__(TPB) void scatter_kernel(
        const ushort* src, ushort* dst, const uint32_t* scanned, int shift) {
    __shared__ uint32_t whist[4 * BINS];
    __shared__ ushort lkeys[TILE];
    __shared__ uint32_t tstart[BINS];
    __shared__ uint32_t gb[BINS];
    __shared__ uint32_t sa[BINS], sb[BINS];

    int tile = blockIdx.x;
    int segL = tile >> 6;
    int tid = threadIdx.x;
    int w = tid >> 6, l = tid & 63;
    uint64_t below = (1ull << l) - 1ull;

    whist[tid] = 0; whist[tid + 256] = 0; whist[tid + 512] = 0; whist[tid + 768] = 0;
    __syncthreads();

    uint32_t keys[IPT];
    uint32_t rnk[IPT];
#pragma unroll
    for (int j = 0; j < IPT; ++j) {
        int posL = w * (64 * IPT) + j * 64 + l;   // tile order: wave-block, iter, lane
        uint32_t key = src[(size_t)tile * TILE + posL];
        uint32_t d = (key >> shift) & 255u;
        uint64_t peers = ~0ull;
#pragma unroll
        for (int bb = 0; bb < 8; ++bb) {
            uint64_t m = __ballot((d >> bb) & 1u);
            peers &= ((d >> bb) & 1u) ? m : ~m;
        }
        uint32_t rig = (uint32_t)__popcll(peers & below);
        uint32_t cnt = (uint32_t)__popcll(peers);
        if (rig == 0) whist[w * BINS + d] += cnt;   // one leader per digit-group
        __builtin_amdgcn_wave_barrier();
        uint32_t h = whist[w * BINS + d];           // same-wave DS ops are ordered
        keys[j] = key;
        rnk[j] = h - cnt + rig;                     // stable rank within wave
    }
    __syncthreads();
    {   // wave-exclusive offsets per digit + tile totals + global bases
        int d = tid;
        uint32_t c0 = whist[d], c1 = whist[BINS + d], c2 = whist[2 * BINS + d], c3 = whist[3 * BINS + d];
        whist[d] = 0;
        whist[BINS + d] = c0;
        whist[2 * BINS + d] = c0 + c1;
        whist[3 * BINS + d] = c0 + c1 + c2;
        sa[d] = c0 + c1 + c2 + c3;
        gb[d] = scanned[(size_t)tile * BINS + d];
    }
    __syncthreads();
    {   // exclusive scan of tile digit totals
        int b = tid;
        uint32_t* cur = sa; uint32_t* nxt = sb;
        for (int off = 1; off < BINS; off <<= 1) {
            uint32_t v = cur[b] + ((b >= off) ? cur[b - off] : 0u);
            nxt[b] = v;
            __syncthreads();
            uint32_t* tmp = cur; cur = nxt; nxt = tmp;
        }
        tstart[b] = (b == 0) ? 0u : cur[b - 1];
    }
    __syncthreads();
#pragma unroll
    for (int j = 0; j < IPT; ++j) {
        uint32_t d = (keys[j] >> shift) & 255u;
        uint32_t lp = tstart[d] + whist[w * BINS + d] + rnk[j];
        lkeys[lp] = (ushort)keys[j];
    }
    __syncthreads();
#pragma unroll
    for (int j = 0; j < IPT; ++j) {
        int i = w * (64 * IPT) + j * 64 + l;
        uint32_t key = lkeys[i];
        uint32_t d = (key >> shift) & 255u;
        uint32_t pos = gb[d] + (uint32_t)i - tstart[d];
        dst[(size_t)segL * N_PER + pos] = (ushort)key;
    }
}

// LDS merge-path integration over sorted u16 keys.
__global__ __launch_bounds__(ITPB) void integ_kernel(
        const ushort* sorted, double* losses, int base_batch) {
    __shared__ ushort lbuf[IBLK + 4];
    __shared__ double red[ITPB];

    int blk = blockIdx.x;
    int bl  = blk / IBPB;
    int pb  = blk % IBPB;
    const ushort* A = sorted + (size_t)(2 * bl) * N_PER;
    const ushort* B = A + N_PER;
    const int n = N_PER;
    int g0 = pb * IBLK;
    int g1 = g0 + IBLK;

    int ia0, ia1;
    {
        int lo = g0 - n; if (lo < 0) lo = 0;
        int hi = g0 < n ? g0 : n;
        while (lo < hi) { int mid = (lo + hi + 1) >> 1; if (A[mid - 1] <= B[g0 - mid]) lo = mid; else hi = mid - 1; }
        ia0 = lo;
    }
    {
        int lo = g1 - n; if (lo < 0) lo = 0;
        int hi = g1 < n ? g1 : n;
        while (lo < hi) { int mid = (lo + hi + 1) >> 1; if (A[mid - 1] <= B[g1 - mid]) lo = mid; else hi = mid - 1; }
        ia1 = lo;
    }
    int jb0 = g0 - ia0, jb1 = g1 - ia1;
    int nA = ia1 - ia0, nB = jb1 - jb0;

    ushort* lA = lbuf;            // lA[0..nA] (sentinel = true next A or 0xFFFF)
    ushort* lB = lbuf + nA + 1;   // lB[0..nB]
    for (int k = threadIdx.x; k <= nA; k += ITPB) {
        int gi = ia0 + k;
        lA[k] = (gi < n) ? A[gi] : (ushort)0xFFFFu;
    }
    for (int k = threadIdx.x; k <= nB; k += ITPB) {
        int gj = jb0 + k;
        lB[k] = (gj < n) ? B[gj] : (ushort)0xFFFFu;
    }
    __syncthreads();

    int t0 = (int)threadIdx.x * TPM;
    int lo = t0 - nB; if (lo < 0) lo = 0;
    int hi = t0 < nA ? t0 : nA;
    while (lo < hi) { int mid = (lo + hi + 1) >> 1; if (lA[mid - 1] <= lB[t0 - mid]) lo = mid; else hi = mid - 1; }
    int li = lo, lj = t0 - lo;

    int p0 = g0 + t0;
    int steps = 2 * n - 1 - p0; if (steps > TPM) steps = TPM;

    uint32_t ca = lA[li], cb = lB[lj];
    uint32_t prev;
    if (ca <= cb) { prev = ca; ++li; ca = lA[li]; }
    else          { prev = cb; ++lj; cb = lB[lj]; }
    int d = (ia0 + li) - (jb0 + lj);
    double acc = 0.0;
    for (int s = 0; s < steps; ++s) {
        bool ta = (ca <= cb);
        uint32_t nxt = ta ? ca : cb;
        float delta = u16f(nxt) - u16f(prev);     // fp32 diff of truncated values
        double dd = (double)d;
        acc += dd * dd * (double)delta;
        if (ta) { ++li; ca = lA[li]; ++d; }
        else    { ++lj; cb = lB[lj]; --d; }
        prev = nxt;
    }

    red[threadIdx.x] = acc;
    __syncthreads();
    for (int off = ITPB / 2; off > 0; off >>= 1) {
        if ((int)threadIdx.x < off) red[threadIdx.x] += red[threadIdx.x + off];
        __syncthreads();
    }
    if (threadIdx.x == 0) atomicAdd(&losses[base_batch + bl], red[0]);
}

__global__ void final_kernel(const double* losses, float* out) {
    int tid = threadIdx.x;   // 64 threads
    const double inv = 1.0 / ((double)N_PER * (double)N_PER);
    double loss = sqrt(losses[tid] * inv);
    for (int off = 32; off > 0; off >>= 1)
        loss += __shfl_down(loss, off);
    if (tid == 0) out[0] = (float)(loss / (double)BATCHES);
}

extern "C" void kernel_launch(void* const* d_in, const int* in_sizes, int n_in,
                              void* d_out, int out_size, void* d_ws, size_t ws_size,
                              hipStream_t stream) {
    const float* t1 = (const float*)d_in[0];
    const float* t2 = (const float*)d_in[1];
    float* out = (float*)d_out;

    char* ws = (char*)d_ws;
    double* losses = (double*)ws;
    size_t off = 1024;
    size_t perBatchKeys = (size_t)2 << LOG_N;                   // 2^19 u16 keys
    size_t perBatchBuf  = perBatchKeys * 2;                     // 1 MB (u16)
    size_t perBatchHist = (size_t)2 * TILES_PER_SEG * BINS * 4; // 128 KB
    size_t perBatch = 2 * perBatchBuf + perBatchHist;

    if (ws_size < off + perBatch) return;   // clean failure > GPU fault

    int CB = (int)((ws_size - off) / perBatch);
    if (CB > BATCHES) CB = BATCHES;
    ushort* bufA = (ushort*)(ws + off);
    ushort* bufB = bufA + (size_t)CB * perBatchKeys;
    uint32_t* hist = (uint32_t*)(bufB + (size_t)CB * perBatchKeys);

    hipLaunchKernelGGL(init_losses, dim3(1), dim3(BATCHES), 0, stream, losses);

    for (int base = 0; base < BATCHES; base += CB) {
        int nb = BATCHES - base < CB ? BATCHES - base : CB;
        int nseg = 2 * nb;
        int ntile = nseg * TILES_PER_SEG;

        // pass 0 (low byte): convert + hist fused, then scan + scatter
        hipLaunchKernelGGL(conv_hist_kernel, dim3(ntile), dim3(TPB), 0, stream,
                           t1, t2, 2 * base, bufA, hist);
        hipLaunchKernelGGL(scan_kernel, dim3(nseg), dim3(BINS), 0, stream, hist);
        hipLaunchKernelGGL(scatter_kernel, dim3(ntile), dim3(TPB), 0, stream,
                           bufA, bufB, hist, 0);
        // pass 1 (high byte)
        hipLaunchKernelGGL(hist_hi_kernel, dim3(ntile), dim3(TPB), 0, stream,
                           bufB, hist);
        hipLaunchKernelGGL(scan_kernel, dim3(nseg), dim3(BINS), 0, stream, hist);
        hipLaunchKernelGGL(scatter_kernel, dim3(ntile), dim3(TPB), 0, stream,
                           bufB, bufA, hist, 8);

        hipLaunchKernelGGL(integ_kernel, dim3(nb * IBPB), dim3(ITPB), 0, stream,
                           bufA, losses, base);
    }
    hipLaunchKernelGGL(final_kernel, dim3(1), dim3(BATCHES), 0, stream, losses, out);
}

// Round 6
// 53.749 us; speedup vs baseline: 17.8780x; 6.3545x over previous
//
#include <hip/hip_runtime.h>
#include <stdint.h>

#define LOG_N   18
#define N_PER   262144              // 2^18 elements per array (H*W)
#define BATCHES 64
#define NBINS   20480               // 2 signs * 80 exponents * 128 mantissa bins
#define HALF    10240
#define HTPB    1024
#define GTPB    1024
#define BPT     (NBINS / GTPB)      // 20 bins per integ thread

__device__ __forceinline__ uint32_t f2u(float f) {
    uint32_t u = __float_as_uint(f);
    return (u & 0x80000000u) ? ~u : (u | 0x80000000u);
}
// float value of a 16-bit truncated key
__device__ __forceinline__ float key2f(uint32_t k16) {
    uint32_t x = k16 << 16;
    uint32_t u = (x & 0x80000000u) ? (x ^ 0x80000000u) : ~x;
    return __uint_as_float(u);
}
// compress u16 key into [0, NBINS): negatives [0x3800,0x6000) -> [0,HALF),
// positives [0xA000,0xC800) -> [HALF,NBINS). Out-of-range (|x|<2^-63 or
// |x|>2^16) clamps to the nearest edge bin: value error <= 2^-63 width.
__device__ __forceinline__ uint32_t comp16(uint32_t k) {
    if (k >= 0x8000u) {
        uint32_t c = (k < 0xA000u) ? 0u : (k - 0xA000u);
        if (c > HALF - 1u) c = HALF - 1u;
        return HALF + c;
    } else {
        int c = (int)k - 0x3800;
        if (c < 0) c = 0;
        if (c > HALF - 1) c = HALF - 1;
        return (uint32_t)c;
    }
}
__device__ __forceinline__ uint32_t dekey(uint32_t c) {
    return (c < HALF) ? (0x3800u + c) : (0xA000u + (c - HALF));
}

// One block per segment: full-segment histogram in LDS (u16-packed pairs,
// 40 KB), streamed float4 input, plain stores to global (no memset needed).
__global__ __launch_bounds__(HTPB) void hist_kernel(
        const float* t1, const float* t2, int base_seg, uint32_t* ghist) {
    __shared__ uint32_t h[NBINS / 2];
    int tid = threadIdx.x;
    for (int i = tid; i < NBINS / 2; i += HTPB) h[i] = 0;
    __syncthreads();
    int segL = blockIdx.x;
    int seg  = base_seg + segL;
    const float4* p = (const float4*)(((seg & 1) ? t2 : t1)
                      + ((size_t)(seg >> 1) << LOG_N));
#pragma unroll 4
    for (int k = 0; k < N_PER / 4 / HTPB; ++k) {   // 64 iterations
        float4 v = p[tid + k * HTPB];
        uint32_t c0 = comp16(f2u(v.x) >> 16);
        uint32_t c1 = comp16(f2u(v.y) >> 16);
        uint32_t c2 = comp16(f2u(v.z) >> 16);
        uint32_t c3 = comp16(f2u(v.w) >> 16);
        atomicAdd(&h[c0 >> 1], 1u << ((c0 & 1) << 4));
        atomicAdd(&h[c1 >> 1], 1u << ((c1 & 1) << 4));
        atomicAdd(&h[c2 >> 1], 1u << ((c2 & 1) << 4));
        atomicAdd(&h[c3 >> 1], 1u << ((c3 & 1) << 4));
    }
    __syncthreads();
    uint2* gh = (uint2*)(ghist + (size_t)segL * NBINS);
    for (int i = tid; i < NBINS / 2; i += HTPB) {
        uint32_t w = h[i];
        uint2 o; o.x = w & 0xFFFFu; o.y = w >> 16;
        gh[i] = o;                                  // coalesced 8B stores
    }
}

// One block per batch: loss = sqrt( sum_k (CA(k)-CB(k))^2 * (val(k+1)-val(k)) / n^2 )
// via register-held per-thread diffs + block scan for the CDF prefix.
__global__ __launch_bounds__(GTPB) void integ_kernel(
        const uint32_t* ghist, double* losses, int base_batch) {
    __shared__ int sa[GTPB], sb[GTPB];
    __shared__ double red[GTPB];
    int bl  = blockIdx.x;
    int tid = threadIdx.x;
    const uint32_t* hA = ghist + (size_t)(2 * bl) * NBINS;
    const uint32_t* hB = hA + NBINS;
    int k0 = tid * BPT;

    int diffs[BPT];
    int s = 0;
#pragma unroll
    for (int k = 0; k < BPT; ++k) {
        int d = (int)hA[k0 + k] - (int)hB[k0 + k];
        diffs[k] = d;
        s += d;
    }
    sa[tid] = s;
    __syncthreads();
    int* cur = sa; int* nxt = sb;
    for (int off = 1; off < GTPB; off <<= 1) {
        int v = cur[tid] + ((tid >= off) ? cur[tid - off] : 0);
        nxt[tid] = v;
        __syncthreads();
        int* tmp = cur; cur = nxt; nxt = tmp;
    }
    int D = (tid == 0) ? 0 : cur[tid - 1];

    double acc = 0.0;
    float vprev = key2f(dekey((uint32_t)k0));
#pragma unroll
    for (int k = 0; k < BPT; ++k) {
        D += diffs[k];
        float vnext = key2f(dekey((uint32_t)(k0 + k + 1)));  // dekey(NBINS)=0xC800, finite
        if (D) {
            double dd = (double)D;
            acc += dd * dd * (double)(vnext - vprev);
        }
        vprev = vnext;
    }

    red[tid] = acc;
    __syncthreads();
    for (int off = GTPB / 2; off > 0; off >>= 1) {
        if (tid < off) red[tid] += red[tid + off];
        __syncthreads();
    }
    if (tid == 0) {
        const double inv = 1.0 / ((double)N_PER * (double)N_PER);
        losses[base_batch + bl] = sqrt(red[0] * inv);
    }
}

__global__ void final_kernel(const double* losses, float* out) {
    int tid = threadIdx.x;   // 64 threads
    double loss = losses[tid];
    for (int off = 32; off > 0; off >>= 1)
        loss += __shfl_down(loss, off);
    if (tid == 0) out[0] = (float)(loss / (double)BATCHES);
}

extern "C" void kernel_launch(void* const* d_in, const int* in_sizes, int n_in,
                              void* d_out, int out_size, void* d_ws, size_t ws_size,
                              hipStream_t stream) {
    const float* t1 = (const float*)d_in[0];
    const float* t2 = (const float*)d_in[1];
    float* out = (float*)d_out;

    char* ws = (char*)d_ws;
    double* losses = (double*)ws;
    size_t off = 1024;
    size_t perBatch = (size_t)2 * NBINS * 4;     // 160 KB (A + B histograms)

    if (ws_size < off + perBatch) return;        // clean failure > GPU fault

    int CB = (int)((ws_size - off) / perBatch);
    if (CB > BATCHES) CB = BATCHES;
    uint32_t* ghist = (uint32_t*)(ws + off);

    for (int base = 0; base < BATCHES; base += CB) {
        int nb = BATCHES - base < CB ? BATCHES - base : CB;
        hipLaunchKernelGGL(hist_kernel, dim3(2 * nb), dim3(HTPB), 0, stream,
                           t1, t2, 2 * base, ghist);
        hipLaunchKernelGGL(integ_kernel, dim3(nb), dim3(GTPB), 0, stream,
                           ghist, losses, base);
    }
    hipLaunchKernelGGL(final_kernel, dim3(1), dim3(BATCHES), 0, stream, losses, out);
}

// Round 7
// 48.078 us; speedup vs baseline: 19.9870x; 1.1180x over previous
//
#include <hip/hip_runtime.h>
#include <stdint.h>

#define LOG_N   18
#define N_PER   262144              // 2^18 elements per array (H*W)
#define BATCHES 64
#define NBINS   20480               // 2 signs * 80 exponents * 128 mantissa bins
#define HALF    10240
#define HTPB    1024
#define SPLITS  4                   // blocks per segment
#define CHUNK   (N_PER / SPLITS)    // 65536 elements per block
#define GTPB    1024
#define BPT     (NBINS / GTPB)      // 20 bins per integ thread

__device__ __forceinline__ uint32_t f2u(float f) {
    uint32_t u = __float_as_uint(f);
    return (u & 0x80000000u) ? ~u : (u | 0x80000000u);
}
// float value of a 16-bit truncated key
__device__ __forceinline__ float key2f(uint32_t k16) {
    uint32_t x = k16 << 16;
    uint32_t u = (x & 0x80000000u) ? (x ^ 0x80000000u) : ~x;
    return __uint_as_float(u);
}
// compress u16 key into [0, NBINS): negatives [0x3800,0x6000) -> [0,HALF),
// positives [0xA000,0xC800) -> [HALF,NBINS). Out-of-range (|x|<2^-63 or
// |x|>2^16) clamps to the nearest edge bin: value error <= 2^-63 width.
__device__ __forceinline__ uint32_t comp16(uint32_t k) {
    if (k >= 0x8000u) {
        uint32_t c = (k < 0xA000u) ? 0u : (k - 0xA000u);
        if (c > HALF - 1u) c = HALF - 1u;
        return HALF + c;
    } else {
        int c = (int)k - 0x3800;
        if (c < 0) c = 0;
        if (c > HALF - 1) c = HALF - 1;
        return (uint32_t)c;
    }
}
__device__ __forceinline__ uint32_t dekey(uint32_t c) {
    return (c < HALF) ? (0x3800u + c) : (0xA000u + (c - HALF));
}

// SPLITS blocks per segment: each block histograms a 256 KB chunk into LDS
// (u16-packed, 40 KB), then zero-skip atomicAdd-merges into the segment's
// global histogram. ghist must be zeroed beforehand.
__global__ __launch_bounds__(HTPB) void hist_kernel(
        const float* t1, const float* t2, int base_seg, uint32_t* ghist) {
    __shared__ uint32_t h[NBINS / 2];
    int tid = threadIdx.x;
    for (int i = tid; i < NBINS / 2; i += HTPB) h[i] = 0;
    __syncthreads();
    int segL = blockIdx.x / SPLITS;
    int part = blockIdx.x % SPLITS;
    int seg  = base_seg + segL;
    const float4* p = (const float4*)(((seg & 1) ? t2 : t1)
                      + ((size_t)(seg >> 1) << LOG_N) + (size_t)part * CHUNK);
#pragma unroll 4
    for (int k = 0; k < CHUNK / 4 / HTPB; ++k) {   // 16 iterations
        float4 v = p[tid + k * HTPB];
        uint32_t c0 = comp16(f2u(v.x) >> 16);
        uint32_t c1 = comp16(f2u(v.y) >> 16);
        uint32_t c2 = comp16(f2u(v.z) >> 16);
        uint32_t c3 = comp16(f2u(v.w) >> 16);
        atomicAdd(&h[c0 >> 1], 1u << ((c0 & 1) << 4));
        atomicAdd(&h[c1 >> 1], 1u << ((c1 & 1) << 4));
        atomicAdd(&h[c2 >> 1], 1u << ((c2 & 1) << 4));
        atomicAdd(&h[c3 >> 1], 1u << ((c3 & 1) << 4));
    }
    __syncthreads();
    uint32_t* gh = ghist + (size_t)segL * NBINS;
    for (int i = tid; i < NBINS / 2; i += HTPB) {
        uint32_t w = h[i];
        if (w) {                                    // zero-skip merge
            uint32_t lo = w & 0xFFFFu, hi = w >> 16;
            if (lo) atomicAdd(&gh[2 * i], lo);
            if (hi) atomicAdd(&gh[2 * i + 1], hi);
        }
    }
}

// One block per batch: loss = sqrt( sum_k (CA(k)-CB(k))^2 * (val(k+1)-val(k)) / n^2 )
// via register-held per-thread diffs + block scan for the CDF prefix.
__global__ __launch_bounds__(GTPB) void integ_kernel(
        const uint32_t* ghist, double* losses, int base_batch) {
    __shared__ int sa[GTPB], sb[GTPB];
    __shared__ double red[GTPB];
    int bl  = blockIdx.x;
    int tid = threadIdx.x;
    const uint32_t* hA = ghist + (size_t)(2 * bl) * NBINS;
    const uint32_t* hB = hA + NBINS;
    int k0 = tid * BPT;

    int diffs[BPT];
    int s = 0;
#pragma unroll
    for (int k = 0; k < BPT; ++k) {
        int d = (int)hA[k0 + k] - (int)hB[k0 + k];
        diffs[k] = d;
        s += d;
    }
    sa[tid] = s;
    __syncthreads();
    int* cur = sa; int* nxt = sb;
    for (int off = 1; off < GTPB; off <<= 1) {
        int v = cur[tid] + ((tid >= off) ? cur[tid - off] : 0);
        nxt[tid] = v;
        __syncthreads();
        int* tmp = cur; cur = nxt; nxt = tmp;
    }
    int D = (tid == 0) ? 0 : cur[tid - 1];

    double acc = 0.0;
    float vprev = key2f(dekey((uint32_t)k0));
#pragma unroll
    for (int k = 0; k < BPT; ++k) {
        D += diffs[k];
        float vnext = key2f(dekey((uint32_t)(k0 + k + 1)));  // dekey(NBINS)=0xC800, finite
        if (D) {
            double dd = (double)D;
            acc += dd * dd * (double)(vnext - vprev);
        }
        vprev = vnext;
    }

    red[tid] = acc;
    __syncthreads();
    for (int off = GTPB / 2; off > 0; off >>= 1) {
        if (tid < off) red[tid] += red[tid + off];
        __syncthreads();
    }
    if (tid == 0) {
        const double inv = 1.0 / ((double)N_PER * (double)N_PER);
        losses[base_batch + bl] = sqrt(red[0] * inv);
    }
}

__global__ void final_kernel(const double* losses, float* out) {
    int tid = threadIdx.x;   // 64 threads
    double loss = losses[tid];
    for (int off = 32; off > 0; off >>= 1)
        loss += __shfl_down(loss, off);
    if (tid == 0) out[0] = (float)(loss / (double)BATCHES);
}

extern "C" void kernel_launch(void* const* d_in, const int* in_sizes, int n_in,
                              void* d_out, int out_size, void* d_ws, size_t ws_size,
                              hipStream_t stream) {
    const float* t1 = (const float*)d_in[0];
    const float* t2 = (const float*)d_in[1];
    float* out = (float*)d_out;

    char* ws = (char*)d_ws;
    double* losses = (double*)ws;
    size_t off = 1024;
    size_t perBatch = (size_t)2 * NBINS * 4;     // 160 KB (A + B histograms)

    if (ws_size < off + perBatch) return;        // clean failure > GPU fault

    int CB = (int)((ws_size - off) / perBatch);
    if (CB > BATCHES) CB = BATCHES;
    uint32_t* ghist = (uint32_t*)(ws + off);

    for (int base = 0; base < BATCHES; base += CB) {
        int nb = BATCHES - base < CB ? BATCHES - base : CB;
        hipMemsetAsync(ghist, 0, (size_t)2 * nb * NBINS * 4, stream);
        hipLaunchKernelGGL(hist_kernel, dim3(2 * nb * SPLITS), dim3(HTPB), 0, stream,
                           t1, t2, 2 * base, ghist);
        hipLaunchKernelGGL(integ_kernel, dim3(nb), dim3(GTPB), 0, stream,
                           ghist, losses, base);
    }
    hipLaunchKernelGGL(final_kernel, dim3(1), dim3(BATCHES), 0, stream, losses, out);
}

// Round 8
// 40.039 us; speedup vs baseline: 23.9997x; 1.2008x over previous
//
#include <hip/hip_runtime.h>
#include <stdint.h>

#define LOG_N   18
#define N_PER   262144              // 2^18 elements per array (H*W)
#define BATCHES 64
#define NBINS   20480               // 2 signs * 80 exponents * 128 mantissa bins
#define HALF    10240
#define HTPB    1024
#define SPLITS  4                   // blocks per segment
#define CHUNK   (N_PER / SPLITS)    // 65536 elements per block
#define GTPB    1024
#define BPT     (NBINS / GTPB)      // 20 bins per integ thread
#define HWORDS  (NBINS / 2)         // packed u16 words per slice

__device__ __forceinline__ uint32_t f2u(float f) {
    uint32_t u = __float_as_uint(f);
    return (u & 0x80000000u) ? ~u : (u | 0x80000000u);
}
// float value of a 16-bit truncated key
__device__ __forceinline__ float key2f(uint32_t k16) {
    uint32_t x = k16 << 16;
    uint32_t u = (x & 0x80000000u) ? (x ^ 0x80000000u) : ~x;
    return __uint_as_float(u);
}
// compress u16 key into [0, NBINS): negatives [0x3800,0x6000) -> [0,HALF),
// positives [0xA000,0xC800) -> [HALF,NBINS). Out-of-range (|x|<2^-63 or
// |x|>2^16) clamps to the nearest edge bin: value error <= 2^-63 width.
__device__ __forceinline__ uint32_t comp16(uint32_t k) {
    if (k >= 0x8000u) {
        uint32_t c = (k < 0xA000u) ? 0u : (k - 0xA000u);
        if (c > HALF - 1u) c = HALF - 1u;
        return HALF + c;
    } else {
        int c = (int)k - 0x3800;
        if (c < 0) c = 0;
        if (c > HALF - 1) c = HALF - 1;
        return (uint32_t)c;
    }
}
__device__ __forceinline__ uint32_t dekey(uint32_t c) {
    return (c < HALF) ? (0x3800u + c) : (0xA000u + (c - HALF));
}

// SPLITS blocks per segment. Unpacked u32 LDS histogram (80 KB -> adjacent
// bins in different banks AND different addresses; 2 blocks/CU). Epilogue:
// plain coalesced stores of a packed-u16 slice — no global atomics, no memset.
__global__ __launch_bounds__(HTPB) void hist_kernel(
        const float* t1, const float* t2, int base_seg, uint32_t* slices) {
    __shared__ uint32_t h[NBINS];
    int tid = threadIdx.x;
    for (int i = tid; i < NBINS; i += HTPB) h[i] = 0;
    __syncthreads();
    int segL = blockIdx.x / SPLITS;
    int part = blockIdx.x % SPLITS;
    int seg  = base_seg + segL;
    const float4* p = (const float4*)(((seg & 1) ? t2 : t1)
                      + ((size_t)(seg >> 1) << LOG_N) + (size_t)part * CHUNK);
#pragma unroll 4
    for (int k = 0; k < CHUNK / 4 / HTPB; ++k) {   // 16 iterations
        float4 v = p[tid + k * HTPB];
        atomicAdd(&h[comp16(f2u(v.x) >> 16)], 1u);
        atomicAdd(&h[comp16(f2u(v.y) >> 16)], 1u);
        atomicAdd(&h[comp16(f2u(v.z) >> 16)], 1u);
        atomicAdd(&h[comp16(f2u(v.w) >> 16)], 1u);
    }
    __syncthreads();
    uint32_t* gs = slices + (size_t)blockIdx.x * HWORDS;
    for (int i = tid; i < HWORDS; i += HTPB)
        gs[i] = h[2 * i] | (h[2 * i + 1] << 16);   // chunk count <= 65536: fits u16
}

// One block per batch: merge the 2*SPLITS packed slices into an LDS diff
// array, then loss = sqrt( sum_k (CA(k)-CB(k))^2 * (val(k+1)-val(k)) / n^2 )
// via register-held per-thread diffs + block scan for the CDF prefix.
__global__ __launch_bounds__(GTPB) void integ_kernel(
        const uint32_t* slices, double* losses, int base_batch) {
    __shared__ short sdiff[NBINS];
    __shared__ int sa[GTPB], sb[GTPB];
    __shared__ double red[GTPB];
    int bl  = blockIdx.x;
    int tid = threadIdx.x;
    const uint32_t* SA = slices + (size_t)(2 * bl) * SPLITS * HWORDS;
    const uint32_t* SB = SA + (size_t)SPLITS * HWORDS;

    // merge slices: thread owns packed words w, w+GTPB, ... (exclusive -> no races)
    for (int w = tid; w < HWORDS; w += GTPB) {
        int d0 = 0, d1 = 0;
#pragma unroll
        for (int s = 0; s < SPLITS; ++s) {
            uint32_t a = SA[s * HWORDS + w];
            uint32_t b = SB[s * HWORDS + w];
            d0 += (int)(a & 0xFFFFu) - (int)(b & 0xFFFFu);
            d1 += (int)(a >> 16)     - (int)(b >> 16);
        }
        sdiff[2 * w]     = (short)d0;
        sdiff[2 * w + 1] = (short)d1;
    }
    __syncthreads();

    int k0 = tid * BPT;
    int diffs[BPT];
    int s = 0;
#pragma unroll
    for (int k = 0; k < BPT; ++k) {
        int d = sdiff[k0 + k];
        diffs[k] = d;
        s += d;
    }
    sa[tid] = s;
    __syncthreads();
    int* cur = sa; int* nxt = sb;
    for (int off = 1; off < GTPB; off <<= 1) {
        int v = cur[tid] + ((tid >= off) ? cur[tid - off] : 0);
        nxt[tid] = v;
        __syncthreads();
        int* tmp = cur; cur = nxt; nxt = tmp;
    }
    int D = (tid == 0) ? 0 : cur[tid - 1];

    double acc = 0.0;
    float vprev = key2f(dekey((uint32_t)k0));
#pragma unroll
    for (int k = 0; k < BPT; ++k) {
        D += diffs[k];
        float vnext = key2f(dekey((uint32_t)(k0 + k + 1)));  // dekey(NBINS)=0xC800, finite
        if (D) {
            double dd = (double)D;
            acc += dd * dd * (double)(vnext - vprev);
        }
        vprev = vnext;
    }

    red[tid] = acc;
    __syncthreads();
    for (int off = GTPB / 2; off > 0; off >>= 1) {
        if (tid < off) red[tid] += red[tid + off];
        __syncthreads();
    }
    if (tid == 0) {
        const double inv = 1.0 / ((double)N_PER * (double)N_PER);
        losses[base_batch + bl] = sqrt(red[0] * inv);
    }
}

__global__ void final_kernel(const double* losses, float* out) {
    int tid = threadIdx.x;   // 64 threads
    double loss = losses[tid];
    for (int off = 32; off > 0; off >>= 1)
        loss += __shfl_down(loss, off);
    if (tid == 0) out[0] = (float)(loss / (double)BATCHES);
}

extern "C" void kernel_launch(void* const* d_in, const int* in_sizes, int n_in,
                              void* d_out, int out_size, void* d_ws, size_t ws_size,
                              hipStream_t stream) {
    const float* t1 = (const float*)d_in[0];
    const float* t2 = (const float*)d_in[1];
    float* out = (float*)d_out;

    char* ws = (char*)d_ws;
    double* losses = (double*)ws;
    size_t off = 1024;
    size_t perBatch = (size_t)2 * SPLITS * HWORDS * 4;   // 320 KB of slices

    if (ws_size < off + perBatch) return;                // clean failure > GPU fault

    int CB = (int)((ws_size - off) / perBatch);
    if (CB > BATCHES) CB = BATCHES;
    uint32_t* slices = (uint32_t*)(ws + off);

    for (int base = 0; base < BATCHES; base += CB) {
        int nb = BATCHES - base < CB ? BATCHES - base : CB;
        hipLaunchKernelGGL(hist_kernel, dim3(2 * nb * SPLITS), dim3(HTPB), 0, stream,
                           t1, t2, 2 * base, slices);
        hipLaunchKernelGGL(integ_kernel, dim3(nb), dim3(GTPB), 0, stream,
                           slices, losses, base);
    }
    hipLaunchKernelGGL(final_kernel, dim3(1), dim3(BATCHES), 0, stream, losses, out);
}